// Round 1
// baseline (602.093 us; speedup 1.0000x reference)
//
#include <hip/hip_runtime.h>
#include <math.h>

#define VPTS 35
#define CIN1 7
#define CH1  16
#define CH2  64
#define DD   10
#define HHH  400
#define WWW  352
#define BN_EPS 1e-5f

// ---------------------------------------------------------------------------
// ws float layout (tiny):
// [0:16)   sum1   [16:32)  sumsq1
// [32:48)  sc1    [48:64)  sh1
// [64:128) sum2   [128:192) sumsq2
// [192:256) sc2   [256:320) sh2
// ---------------------------------------------------------------------------

// Stage-1 stats: per-point relu(x@w1+b1), reduce sum/sumsq per channel.
__global__ void __launch_bounds__(256) k_stats1(
    const float* __restrict__ feat,
    const float* __restrict__ w1, const float* __restrict__ b1,
    float* __restrict__ red1, int KP) {
  int idx = blockIdx.x * blockDim.x + threadIdx.x;
  float pw[CH1];
  if (idx < KP) {
    float x[CIN1];
#pragma unroll
    for (int i = 0; i < CIN1; ++i) x[i] = feat[(size_t)idx * CIN1 + i];
#pragma unroll
    for (int c = 0; c < CH1; ++c) {
      float acc = b1[c];
#pragma unroll
      for (int i = 0; i < CIN1; ++i) acc = fmaf(x[i], w1[i * CH1 + c], acc);
      pw[c] = fmaxf(acc, 0.f);
    }
  } else {
#pragma unroll
    for (int c = 0; c < CH1; ++c) pw[c] = 0.f;
  }
  __shared__ float ssum[2 * CH1];
  if (threadIdx.x < 2 * CH1) ssum[threadIdx.x] = 0.f;
  __syncthreads();
#pragma unroll
  for (int c = 0; c < CH1; ++c) {
    float s = pw[c], q = pw[c] * pw[c];
    for (int o = 32; o > 0; o >>= 1) {
      s += __shfl_down(s, o);
      q += __shfl_down(q, o);
    }
    if ((threadIdx.x & 63) == 0) {
      atomicAdd(&ssum[c], s);
      atomicAdd(&ssum[CH1 + c], q);
    }
  }
  __syncthreads();
  if (threadIdx.x < 2 * CH1) atomicAdd(&red1[threadIdx.x], ssum[threadIdx.x]);
}

// Fold batch stats into scale/shift: sc = g*rsqrt(var+eps), sh = be - mean*sc
__global__ void k_finalize(const float* __restrict__ red,
                           const float* __restrict__ g,
                           const float* __restrict__ be,
                           float* __restrict__ scsh, int CH, float invN) {
  int c = threadIdx.x;
  if (c < CH) {
    float mean = red[c] * invN;
    float var = red[CH + c] * invN - mean * mean;
    float inv = rsqrtf(var + BN_EPS);
    float sc = g[c] * inv;
    scsh[c] = sc;
    scsh[CH + c] = be[c] - mean * sc;
  }
}

// Shared VFE-1 pipeline: feat -> mask, pw1n (BN'd), agg1, x2 = concat*mask
__device__ __forceinline__ void compute_x2(
    const float* __restrict__ feat, int k, int t,
    const float* __restrict__ w1, const float* __restrict__ b1,
    const float* __restrict__ scsh1,
    float* fs, float* mask_s, float* pw1_s, float* agg1_s, float* x2_s) {
  if (t < VPTS * CIN1) fs[t] = feat[(size_t)k * (VPTS * CIN1) + t];
  __syncthreads();
  if (t < VPTS) {
    float m = fs[t * CIN1];
#pragma unroll
    for (int i = 1; i < CIN1; ++i) m = fmaxf(m, fs[t * CIN1 + i]);
    mask_s[t] = (m != 0.f) ? 1.f : 0.f;
  }
  for (int i = t; i < VPTS * CH1; i += 256) {
    int p = i >> 4, c = i & 15;
    float acc = b1[c];
#pragma unroll
    for (int j = 0; j < CIN1; ++j) acc = fmaf(fs[p * CIN1 + j], w1[j * CH1 + c], acc);
    acc = fmaxf(acc, 0.f);
    pw1_s[i] = fmaf(acc, scsh1[c], scsh1[CH1 + c]);
  }
  __syncthreads();
  if (t < CH1) {
    float m = pw1_s[t];
    for (int p = 1; p < VPTS; ++p) m = fmaxf(m, pw1_s[p * CH1 + t]);
    agg1_s[t] = m;
  }
  __syncthreads();
  for (int i = t; i < VPTS * 32; i += 256) {
    int p = i >> 5, c = i & 31;
    x2_s[i] = (c < CH1 ? pw1_s[p * CH1 + c] : agg1_s[c - CH1]) * mask_s[p];
  }
  __syncthreads();
}

// Stage-2 stats: recompute x2 per voxel, pw2=relu(x2@w2+b2), sum/sumsq (64ch)
__global__ void __launch_bounds__(256) k_stats2(
    const float* __restrict__ feat,
    const float* __restrict__ w1, const float* __restrict__ b1,
    const float* __restrict__ scsh1,
    const float* __restrict__ w2, const float* __restrict__ b2,
    float* __restrict__ red2) {
  __shared__ float fs[VPTS * CIN1], mask_s[VPTS], pw1_s[VPTS * CH1], agg1_s[CH1];
  __shared__ float x2_s[VPTS * 32];
  __shared__ float w2_s[32 * CH2];
  __shared__ float ss[2 * CH2];
  int k = blockIdx.x, t = threadIdx.x;
  for (int i = t; i < 32 * CH2; i += 256) w2_s[i] = w2[i];
  if (t < 2 * CH2) ss[t] = 0.f;
  compute_x2(feat, k, t, w1, b1, scsh1, fs, mask_s, pw1_s, agg1_s, x2_s);
  int c = t & 63;
  float wcol[32];
#pragma unroll
  for (int i = 0; i < 32; ++i) wcol[i] = w2_s[i * CH2 + c];
  float bb = b2[c];
  float lsum = 0.f, lsq = 0.f;
  for (int idx = t; idx < VPTS * CH2; idx += 256) {
    int p = idx >> 6;
    float acc = bb;
#pragma unroll
    for (int i = 0; i < 32; ++i) acc = fmaf(x2_s[p * 32 + i], wcol[i], acc);
    acc = fmaxf(acc, 0.f);
    lsum += acc;
    lsq = fmaf(acc, acc, lsq);
  }
  atomicAdd(&ss[c], lsum);
  atomicAdd(&ss[CH2 + c], lsq);
  __syncthreads();
  if (t < 2 * CH2) atomicAdd(&red2[t], ss[t]);
}

// Final: recompute x2, pw2n (BN'd), agg2, voxelwise masked max, scatter-add.
__global__ void __launch_bounds__(256) k_final(
    const float* __restrict__ feat,
    const float* __restrict__ w1, const float* __restrict__ b1,
    const float* __restrict__ scsh1,
    const float* __restrict__ w2, const float* __restrict__ b2,
    const float* __restrict__ scsh2,
    const int* __restrict__ coord,
    float* __restrict__ out) {
  __shared__ float fs[VPTS * CIN1], mask_s[VPTS], pw1_s[VPTS * CH1], agg1_s[CH1];
  __shared__ float x2_s[VPTS * 32];
  __shared__ float w2_s[32 * CH2];
  __shared__ float pw2_s[VPTS * CH2];
  __shared__ float agg2_s[CH2];
  int k = blockIdx.x, t = threadIdx.x;
  for (int i = t; i < 32 * CH2; i += 256) w2_s[i] = w2[i];
  compute_x2(feat, k, t, w1, b1, scsh1, fs, mask_s, pw1_s, agg1_s, x2_s);
  int c = t & 63;
  float wcol[32];
#pragma unroll
  for (int i = 0; i < 32; ++i) wcol[i] = w2_s[i * CH2 + c];
  float bb = b2[c];
  float sc = scsh2[c], sh = scsh2[CH2 + c];
  for (int idx = t; idx < VPTS * CH2; idx += 256) {
    int p = idx >> 6;
    float acc = bb;
#pragma unroll
    for (int i = 0; i < 32; ++i) acc = fmaf(x2_s[p * 32 + i], wcol[i], acc);
    acc = fmaxf(acc, 0.f);
    pw2_s[idx] = fmaf(acc, sc, sh);
  }
  __syncthreads();
  if (t < CH2) {
    float m = pw2_s[t];
    for (int p = 1; p < VPTS; ++p) m = fmaxf(m, pw2_s[p * CH2 + t]);
    agg2_s[t] = m;
  }
  __syncthreads();
  if (t < 2 * CH2) {
    float vm = -INFINITY;
    if (t < CH2) {
      for (int p = 0; p < VPTS; ++p) vm = fmaxf(vm, pw2_s[p * CH2 + t] * mask_s[p]);
    } else {
      float a = agg2_s[t - CH2];
      for (int p = 0; p < VPTS; ++p) vm = fmaxf(vm, a * mask_s[p]);
    }
    int4 cc = *reinterpret_cast<const int4*>(coord + (size_t)k * 4);
    long vox = ((long)(cc.x * DD + cc.y) * HHH + cc.z) * WWW + cc.w;
    atomicAdd(&out[vox * (2 * CH2) + t], vm);
  }
}

extern "C" void kernel_launch(void* const* d_in, const int* in_sizes, int n_in,
                              void* d_out, int out_size, void* d_ws, size_t ws_size,
                              hipStream_t stream) {
  const float* feat = (const float*)d_in[0];
  const int* coord  = (const int*)d_in[1];
  const float* w1  = (const float*)d_in[3];
  const float* b1  = (const float*)d_in[4];
  const float* g1  = (const float*)d_in[5];
  const float* be1 = (const float*)d_in[6];
  const float* w2  = (const float*)d_in[7];
  const float* b2  = (const float*)d_in[8];
  const float* g2  = (const float*)d_in[9];
  const float* be2 = (const float*)d_in[10];
  float* out = (float*)d_out;
  float* ws = (float*)d_ws;

  int K = in_sizes[0] / (VPTS * CIN1);
  int KP = K * VPTS;

  float* red1  = ws;         // 32
  float* scsh1 = ws + 32;    // 32
  float* red2  = ws + 64;    // 128
  float* scsh2 = ws + 192;   // 128

  hipMemsetAsync(out, 0, (size_t)out_size * sizeof(float), stream);
  hipMemsetAsync(ws, 0, 320 * sizeof(float), stream);

  k_stats1<<<(KP + 255) / 256, 256, 0, stream>>>(feat, w1, b1, red1, KP);
  k_finalize<<<1, 64, 0, stream>>>(red1, g1, be1, scsh1, CH1, 1.f / (float)KP);
  k_stats2<<<K, 256, 0, stream>>>(feat, w1, b1, scsh1, w2, b2, red2);
  k_finalize<<<1, 64, 0, stream>>>(red2, g2, be2, scsh2, CH2, 1.f / (float)KP);
  k_final<<<K, 256, 0, stream>>>(feat, w1, b1, scsh1, w2, b2, scsh2, coord, out);
}